// Round 1
// baseline (2079.084 us; speedup 1.0000x reference)
//
#include <hip/hip_runtime.h>
#include <math.h>

#define Bn 2
#define CIc 256
#define COc 256
#define Hh 128
#define Ww 128
#define HW (Hh*Ww)
#define PT 16

// ws layout (in floats):
//  wofft : [CI][3x3][27]      62208
//  wt    : [9][CI][CO]        589824
//  scale : [CO]               256
//  shift : [CO]               256
//  py    : [B][9][HW]         294912
//  px    : [B][9][HW]         294912
//  mask  : [B][9][HW]         294912
// total ~1.54M floats = 6.15 MB
#define WOFFT_OFF 0
#define WT_OFF    62208
#define SCALE_OFF (WT_OFF + 9*CIc*COc)
#define SHIFT_OFF (SCALE_OFF + COc)
#define PY_OFF    (SHIFT_OFF + COc)
#define PX_OFF    (PY_OFF + Bn*9*HW)
#define MASK_OFF  (PX_OFF + Bn*9*HW)

__global__ void prep_kernel(const float* __restrict__ w_off,
                            const float* __restrict__ w_dcn,
                            const float* __restrict__ b_dcn,
                            const float* __restrict__ gamma,
                            const float* __restrict__ beta,
                            const float* __restrict__ rmean,
                            const float* __restrict__ rvar,
                            float* __restrict__ ws) {
    int tid = blockIdx.x * blockDim.x + threadIdx.x;
    int nthreads = gridDim.x * blockDim.x;
    // wofft[ci][kk][oc] = w_off[oc][ci][kk]
    for (int idx = tid; idx < CIc*9*27; idx += nthreads) {
        int oc = idx % 27;
        int r  = idx / 27;      // r = ci*9 + kk
        int kk = r % 9;
        int ci = r / 9;
        ws[WOFFT_OFF + idx] = w_off[oc*CIc*9 + ci*9 + kk];
    }
    // wt[k][ci][co] = w_dcn[co][ci][k]
    for (int idx = tid; idx < 9*CIc*COc; idx += nthreads) {
        int co = idx % COc;
        int r  = idx / COc;
        int ci = r % CIc;
        int k  = r / CIc;
        ws[WT_OFF + idx] = w_dcn[co*CIc*9 + ci*9 + k];
    }
    if (tid < COc) {
        float inv = gamma[tid] * rsqrtf(rvar[tid] + 1e-5f);
        ws[SCALE_OFF + tid] = inv;
        ws[SHIFT_OFF + tid] = beta[tid] - rmean[tid]*inv + b_dcn[tid]*inv;
    }
}

// Offset conv: one thread per pixel, 27 accumulators.
// Writes absolute sample coords py/px and sigmoid mask to ws.
__global__ __launch_bounds__(128) void offconv_kernel(const float* __restrict__ x,
                                                      const float* __restrict__ b_off,
                                                      float* __restrict__ ws) {
    int w = threadIdx.x;      // 0..127
    int h = blockIdx.x;       // 0..127
    int b = blockIdx.y;
    const float* xb = x + (size_t)b*CIc*HW;
    const float* wofft = ws + WOFFT_OFF;

    float acc[27];
    #pragma unroll
    for (int i = 0; i < 27; i++) acc[i] = 0.f;

    for (int ci = 0; ci < CIc; ci++) {
        const float* xc = xb + ci*HW;
        const float* wp = wofft + ci*9*27;
        #pragma unroll
        for (int ky = 0; ky < 3; ky++) {
            int y = h + ky - 1;
            if ((unsigned)y < Hh) {
                const float* xr = xc + y*Ww;
                float x0 = (w >= 1)      ? xr[w-1] : 0.f;
                float x1 =                 xr[w];
                float x2 = (w <= Ww-2)   ? xr[w+1] : 0.f;
                const float* wk = wp + ky*3*27;
                #pragma unroll
                for (int oc = 0; oc < 27; oc++) acc[oc] += x0 * wk[oc];
                #pragma unroll
                for (int oc = 0; oc < 27; oc++) acc[oc] += x1 * wk[27+oc];
                #pragma unroll
                for (int oc = 0; oc < 27; oc++) acc[oc] += x2 * wk[54+oc];
            }
        }
    }

    int pix = h*Ww + w;
    float* py = ws + PY_OFF   + (size_t)b*9*HW;
    float* px = ws + PX_OFF   + (size_t)b*9*HW;
    float* mk = ws + MASK_OFF + (size_t)b*9*HW;
    #pragma unroll
    for (int k = 0; k < 9; k++) {
        float dy = acc[2*k]   + b_off[2*k];
        float dx = acc[2*k+1] + b_off[2*k+1];
        float mv = acc[18+k]  + b_off[18+k];
        mv = 1.f / (1.f + __expf(-mv));
        py[k*HW + pix] = (float)(h - 1 + k/3) + dy;
        px[k*HW + pix] = (float)(w - 1 + k%3) + dx;
        mk[k*HW + pix] = mv;
    }
}

// Main deformable conv: block = 16 pixels x all 256 co.
// Per k: stage masked bilinear val[256ci][16px] in LDS, then fp32 GEMM accumulate.
__global__ __launch_bounds__(256) void dconv_kernel(const float* __restrict__ x,
                                                    const float* __restrict__ ws,
                                                    float* __restrict__ out) {
    __shared__ float val[CIc*PT];       // 16 KB
    __shared__ float spy[9*PT], spx[9*PT], smk[9*PT];

    int tid  = threadIdx.x;
    int tile = blockIdx.x;              // 0 .. B*HW/PT-1
    int b    = tile / (HW/PT);
    int pixbase = (tile % (HW/PT)) * PT;
    const float* xb = x + (size_t)b*CIc*HW;

    if (tid < 9*PT) {
        int k = tid / PT, p = tid % PT;
        size_t o = (size_t)b*9*HW + k*HW + pixbase + p;
        spy[tid] = ws[PY_OFF + o];
        spx[tid] = ws[PX_OFF + o];
        smk[tid] = ws[MASK_OFF + o];
    }
    __syncthreads();

    float acc[PT];
    #pragma unroll
    for (int p = 0; p < PT; p++) acc[p] = 0.f;

    int co   = tid;
    int px_l = tid & (PT-1);     // staging: pixel lane
    int ci0  = tid >> 4;         // staging: ci group 0..15

    for (int k = 0; k < 9; k++) {
        // ---- sample params (per pixel, reused across all ci) ----
        float pyv = spy[k*PT + px_l];
        float pxv = spx[k*PT + px_l];
        float mv  = smk[k*PT + px_l];
        float y0f = floorf(pyv), x0f = floorf(pxv);
        float ly = pyv - y0f, lx = pxv - x0f;
        int y0 = (int)y0f, x0i = (int)x0f;
        int y1 = y0 + 1,   x1i = x0i + 1;
        float wy0 = ((unsigned)y0  < Hh) ? (1.f-ly) : 0.f;
        float wy1 = ((unsigned)y1  < Hh) ? ly       : 0.f;
        float wx0 = ((unsigned)x0i < Ww) ? (1.f-lx) : 0.f;
        float wx1 = ((unsigned)x1i < Ww) ? lx       : 0.f;
        float w00 = wy0*wx0*mv, w01 = wy0*wx1*mv;
        float w10 = wy1*wx0*mv, w11 = wy1*wx1*mv;
        int cy0 = min(max(y0, 0), Hh-1), cy1 = min(max(y1, 0), Hh-1);
        int cx0 = min(max(x0i,0), Ww-1), cx1 = min(max(x1i,0), Ww-1);
        int b00 = cy0*Ww+cx0, b01 = cy0*Ww+cx1;
        int b10 = cy1*Ww+cx0, b11 = cy1*Ww+cx1;

        __syncthreads();   // previous GEMM done before overwriting val
        // ---- stage: 16 ci per iteration, lanes span 16px x 4ci ----
        for (int it = 0; it < CIc/16; it++) {
            int ci = it*16 + ci0;
            const float* xc = xb + ci*HW;
            float v = w00*xc[b00] + w01*xc[b01] + w10*xc[b10] + w11*xc[b11];
            val[ci*PT + px_l] = v;
        }
        __syncthreads();

        // ---- GEMM accumulate: thread = co, 16 px ----
        const float* wp = ws + WT_OFF + (size_t)(k*CIc)*COc + co;
        #pragma unroll 4
        for (int ci = 0; ci < CIc; ci++) {
            float wv = wp[ci*COc];
            const float4* vp = (const float4*)&val[ci*PT];
            float4 v0 = vp[0], v1 = vp[1], v2 = vp[2], v3 = vp[3];
            acc[0]  += wv*v0.x;  acc[1]  += wv*v0.y;  acc[2]  += wv*v0.z;  acc[3]  += wv*v0.w;
            acc[4]  += wv*v1.x;  acc[5]  += wv*v1.y;  acc[6]  += wv*v1.z;  acc[7]  += wv*v1.w;
            acc[8]  += wv*v2.x;  acc[9]  += wv*v2.y;  acc[10] += wv*v2.z;  acc[11] += wv*v2.w;
            acc[12] += wv*v3.x;  acc[13] += wv*v3.y;  acc[14] += wv*v3.z;  acc[15] += wv*v3.w;
        }
    }

    // ---- epilogue: BN + bias + ReLU ----
    float sc = ws[SCALE_OFF + co];
    float sh = ws[SHIFT_OFF + co];
    float* op = out + ((size_t)b*COc + co)*HW + pixbase;
    #pragma unroll
    for (int p = 0; p < PT; p++) {
        op[p] = fmaxf(acc[p]*sc + sh, 0.f);
    }
}

extern "C" void kernel_launch(void* const* d_in, const int* in_sizes, int n_in,
                              void* d_out, int out_size, void* d_ws, size_t ws_size,
                              hipStream_t stream) {
    const float* x     = (const float*)d_in[0];
    const float* w_off = (const float*)d_in[1];
    const float* b_off = (const float*)d_in[2];
    const float* w_dcn = (const float*)d_in[3];
    const float* b_dcn = (const float*)d_in[4];
    const float* gamma = (const float*)d_in[5];
    const float* beta  = (const float*)d_in[6];
    const float* rmean = (const float*)d_in[7];
    const float* rvar  = (const float*)d_in[8];
    float* out = (float*)d_out;
    float* ws  = (float*)d_ws;

    prep_kernel<<<1024, 256, 0, stream>>>(w_off, w_dcn, b_dcn, gamma, beta, rmean, rvar, ws);
    offconv_kernel<<<dim3(Hh, Bn), 128, 0, stream>>>(x, b_off, ws);
    dconv_kernel<<<Bn*HW/PT, 256, 0, stream>>>(x, ws, out);
}

// Round 2
// 378.431 us; speedup vs baseline: 5.4940x; 5.4940x over previous
//
#include <hip/hip_runtime.h>
#include <math.h>

#define Bn 2
#define CIc 256
#define COc 256
#define Hh 128
#define Ww 128
#define HW (Hh*Ww)

typedef unsigned short u16;
typedef unsigned int u32;

// ws layout (float offsets)
#define WOFP_OFF 0                        // 9*8*32*4*8 u16 = 73728 u16 = 36864 f
#define WPACK_OFF 36864                   // 9*8*256*4*8 u16 = 589824 u16 = 294912 f
#define SCALE_OFF (WPACK_OFF + 294912)    // 331776
#define SHIFT_OFF (SCALE_OFF + COc)       // 332032
#define PY_OFF   (SHIFT_OFF + COc)        // 332288
#define PX_OFF   (PY_OFF + Bn*9*HW)       // +294912
#define MASK_OFF (PX_OFF + Bn*9*HW)

typedef __bf16 bf16x8 __attribute__((ext_vector_type(8)));
typedef float  f32x4  __attribute__((ext_vector_type(4)));

__device__ __forceinline__ u16 f2bf(float f) {
    u32 u = __builtin_bit_cast(u32, f);
    return (u16)((u + 0x7FFFu + ((u >> 16) & 1u)) >> 16);
}

__global__ void prep_kernel(const float* __restrict__ w_off,
                            const float* __restrict__ w_dcn,
                            const float* __restrict__ b_dcn,
                            const float* __restrict__ gamma,
                            const float* __restrict__ beta,
                            const float* __restrict__ rmean,
                            const float* __restrict__ rvar,
                            float* __restrict__ ws) {
    int tid = blockIdx.x*blockDim.x + threadIdx.x;
    int nth = gridDim.x*blockDim.x;
    u16* wofp = (u16*)(ws + WOFP_OFF);
    u16* wpk  = (u16*)(ws + WPACK_OFF);
    // woffpack: flat = (((k*8+s)*32+co)*4+kb)*8+j ; ci = s*32+kb*8+j ; co>=27 -> 0
    for (int idx = tid; idx < 9*8*32*4*8; idx += nth) {
        int j = idx & 7, kb = (idx>>3)&3, co = (idx>>5)&31, s = (idx>>10)&7, k = idx>>13;
        int ci = s*32 + kb*8 + j;
        float v = (co < 27) ? w_off[(co*CIc + ci)*9 + k] : 0.f;
        wofp[idx] = f2bf(v);
    }
    // wpack: flat = (((k*8+s)*256+co)*4+kb)*8+j
    for (int idx = tid; idx < 9*8*256*4*8; idx += nth) {
        int j = idx & 7, kb = (idx>>3)&3, co = (idx>>5)&255, s = (idx>>13)&7, k = idx>>16;
        int ci = s*32 + kb*8 + j;
        wpk[idx] = f2bf(w_dcn[(co*CIc + ci)*9 + k]);
    }
    if (tid < COc) {
        float inv = gamma[tid] * rsqrtf(rvar[tid] + 1e-5f);
        ws[SCALE_OFF+tid] = inv;
        ws[SHIFT_OFF+tid] = beta[tid] - rmean[tid]*inv + b_dcn[tid]*inv;
    }
}

// Offset conv via MFMA: block = 64 px, M=32 (27 used), K=2304 (9 taps x 256 ci).
__global__ __launch_bounds__(256, 4) void offconv_kernel(const float* __restrict__ x,
                                                         const float* __restrict__ b_off,
                                                         float* __restrict__ ws) {
    __shared__ u16 sval[16384];      // [px64][ci256] bf16, 512B rows, XOR-swizzled
    __shared__ float fin[32][64];

    int tid = threadIdx.x;
    int tile = blockIdx.x;           // 512 blocks
    int b = tile >> 8;
    int pixbase = (tile & 255) * 64;
    const float* xb = x + (size_t)b*CIc*HW;
    const u16* wofp = (const u16*)(ws + WOFP_OFF);

    int h  = pixbase >> 7;           // uniform per block
    int w0 = pixbase & 127;          // 0 or 64
    int l  = tid & 63;
    int wv = tid >> 6;

    // staging ids: px = 32px-from-low5 + bit from tid.7 ; cg2 = 32-ci groups (x2 halves)
    int spx = (tid & 31) | ((tid >> 2) & 32);
    int cg2 = (tid >> 5) & 3;
    u32 wswz = (u32)(spx & 7) << 4;
    int xw_lane = w0 + spx;

    // gemm ids
    int pxl = wv*16 + (l & 15);
    u32 rswz = (u32)(pxl & 7) << 4;
    int kb = l >> 4;
    u32 aoff = (u32)(((l & 15)*4 + kb) * 8);
    u32 bb_l = (u32)pxl*512 + (u32)kb*16;

    f32x4 acc[2];
    acc[0] = (f32x4){0.f,0.f,0.f,0.f};
    acc[1] = (f32x4){0.f,0.f,0.f,0.f};

    for (int k = 0; k < 9; k++) {
        int i = k/3, j = k - 3*i;
        int y = h + i - 1;
        int xw = xw_lane + j - 1;
        bool ok = ((unsigned)y < Hh) && ((unsigned)xw < Ww);
        const float* xr = xb + y*Ww + xw;
        __syncthreads();
        #pragma unroll
        for (int half = 0; half < 2; half++) {
            int cib = half*128 + cg2*32;
            u32 wb = ((u32)spx*512 + (u32)cib*2);
            #pragma unroll 4
            for (int it = 0; it < 16; it++) {
                int ci = cib + it*2;
                float v0 = ok ? xr[(size_t)ci*HW] : 0.f;
                float v1 = ok ? xr[(size_t)(ci+1)*HW] : 0.f;
                u32 pk = (u32)f2bf(v0) | ((u32)f2bf(v1) << 16);
                *(u32*)((char*)sval + ((wb + (u32)it*4) ^ wswz)) = pk;
            }
        }
        __syncthreads();
        const u16* wk = wofp + (size_t)k*8192 + aoff;
        char* sv = (char*)sval;
        #pragma unroll
        for (int s = 0; s < 8; s++) {
            bf16x8 a0 = *(const bf16x8*)(wk + s*1024);
            bf16x8 a1 = *(const bf16x8*)(wk + s*1024 + 512);
            bf16x8 bf = *(const bf16x8*)(sv + ((bb_l + (u32)s*64) ^ rswz));
            acc[0] = __builtin_amdgcn_mfma_f32_16x16x32_bf16(a0, bf, acc[0], 0,0,0);
            acc[1] = __builtin_amdgcn_mfma_f32_16x16x32_bf16(a1, bf, acc[1], 0,0,0);
        }
    }
    int rbase = kb*4;
    #pragma unroll
    for (int mi = 0; mi < 2; mi++)
        #pragma unroll
        for (int r = 0; r < 4; r++)
            fin[mi*16 + rbase + r][pxl] = acc[mi][r];
    __syncthreads();
    for (int idx = tid; idx < 9*64; idx += 256) {
        int k = idx >> 6, p = idx & 63;
        int pix = pixbase + p;
        float dy = fin[2*k][p]   + b_off[2*k];
        float dx = fin[2*k+1][p] + b_off[2*k+1];
        float mv = fin[18+k][p]  + b_off[18+k];
        mv = 1.f/(1.f+__expf(-mv));
        size_t o = (size_t)b*9*HW + (size_t)k*HW + pix;
        ws[PY_OFF+o]   = (float)(h - 1 + k/3) + dy;
        ws[PX_OFF+o]   = (float)((pix & 127) - 1 + k%3) + dx;
        ws[MASK_OFF+o] = mv;
    }
}

// Deformable conv via MFMA: block = 32 px x 256 co, 4 waves (each 64 co x 32 px).
__global__ __launch_bounds__(256, 4) void dconv_kernel(const float* __restrict__ x,
                                                       const float* __restrict__ ws,
                                                       float* __restrict__ out) {
    __shared__ u16 sval[8192];       // [px32][ci256] bf16, 512B rows, XOR-swizzled
    __shared__ float spy[288], spxs[288], smk[288];

    int tid = threadIdx.x;
    int tile = blockIdx.x;           // 1024 blocks
    int b = tile >> 9;
    int pixbase = (tile & 511) * 32;
    const float* xb = x + (size_t)b*CIc*HW;
    const u16* wpk = (const u16*)(ws + WPACK_OFF);

    for (int idx = tid; idx < 288; idx += 256) {
        int k = idx >> 5, p = idx & 31;
        size_t o = (size_t)b*9*HW + (size_t)k*HW + pixbase + p;
        spy[idx]  = ws[PY_OFF+o];
        spxs[idx] = ws[PX_OFF+o];
        smk[idx]  = ws[MASK_OFF+o];
    }

    int l  = tid & 63;
    int wv = tid >> 6;
    int wco = wv * 64;

    int sp = tid & 31;               // staging px lane
    int cg = tid >> 5;               // 0..7, 32 ci each
    u32 wbase = (u32)sp*512 + (u32)cg*64;
    u32 wswz = (u32)(sp & 7) << 4;

    int pxl = l & 15;
    int kb = l >> 4;
    u32 rswz = (u32)(pxl & 7) << 4;
    u32 aoff = (u32)(((l & 15)*4 + kb) * 8);
    u32 bb_l = (u32)pxl*512 + (u32)kb*16;

    f32x4 acc[4][2];
    #pragma unroll
    for (int mi = 0; mi < 4; mi++) {
        acc[mi][0] = (f32x4){0.f,0.f,0.f,0.f};
        acc[mi][1] = (f32x4){0.f,0.f,0.f,0.f};
    }

    for (int k = 0; k < 9; k++) {
        __syncthreads();             // params ready (k=0) / prev GEMM reads done
        float pyv = spy[k*32+sp], pxv = spxs[k*32+sp], mv = smk[k*32+sp];
        float y0f = floorf(pyv), x0f = floorf(pxv);
        float ly = pyv - y0f, lx = pxv - x0f;
        int y0 = (int)y0f, x0i = (int)x0f;
        int y1 = y0 + 1, x1i = x0i + 1;
        float wy0 = ((unsigned)y0  < Hh) ? (1.f-ly) : 0.f;
        float wy1 = ((unsigned)y1  < Hh) ? ly       : 0.f;
        float wx0 = ((unsigned)x0i < Ww) ? (1.f-lx) : 0.f;
        float wx1 = ((unsigned)x1i < Ww) ? lx       : 0.f;
        float w00 = wy0*wx0*mv, w01 = wy0*wx1*mv, w10 = wy1*wx0*mv, w11 = wy1*wx1*mv;
        int cy0 = min(max(y0,0),Hh-1), cy1 = min(max(y1,0),Hh-1);
        int cx0 = min(max(x0i,0),Ww-1), cx1 = min(max(x1i,0),Ww-1);
        int b00 = cy0*Ww+cx0, b01 = cy0*Ww+cx1, b10 = cy1*Ww+cx0, b11 = cy1*Ww+cx1;

        const float* xc = xb + (size_t)cg*32*HW;
        #pragma unroll 4
        for (int it = 0; it < 16; it++) {
            const float* p0 = xc + (size_t)(2*it)*HW;
            const float* p1 = p0 + HW;
            float v0 = w00*p0[b00] + w01*p0[b01] + w10*p0[b10] + w11*p0[b11];
            float v1 = w00*p1[b00] + w01*p1[b01] + w10*p1[b10] + w11*p1[b11];
            u32 pk = (u32)f2bf(v0) | ((u32)f2bf(v1) << 16);
            *(u32*)((char*)sval + ((wbase + (u32)it*4) ^ wswz)) = pk;
        }
        __syncthreads();

        const u16* wk = wpk + (size_t)k*65536 + (u32)wv*2048 + aoff;
        char* sv = (char*)sval;
        #pragma unroll
        for (int s = 0; s < 8; s++) {
            bf16x8 a0 = *(const bf16x8*)(wk + s*8192);
            bf16x8 a1 = *(const bf16x8*)(wk + s*8192 + 512);
            bf16x8 a2 = *(const bf16x8*)(wk + s*8192 + 1024);
            bf16x8 a3 = *(const bf16x8*)(wk + s*8192 + 1536);
            u32 bof = (bb_l + (u32)s*64) ^ rswz;
            bf16x8 b0 = *(const bf16x8*)(sv + bof);
            bf16x8 b1 = *(const bf16x8*)(sv + bof + 8192);
            acc[0][0] = __builtin_amdgcn_mfma_f32_16x16x32_bf16(a0,b0,acc[0][0],0,0,0);
            acc[0][1] = __builtin_amdgcn_mfma_f32_16x16x32_bf16(a0,b1,acc[0][1],0,0,0);
            acc[1][0] = __builtin_amdgcn_mfma_f32_16x16x32_bf16(a1,b0,acc[1][0],0,0,0);
            acc[1][1] = __builtin_amdgcn_mfma_f32_16x16x32_bf16(a1,b1,acc[1][1],0,0,0);
            acc[2][0] = __builtin_amdgcn_mfma_f32_16x16x32_bf16(a2,b0,acc[2][0],0,0,0);
            acc[2][1] = __builtin_amdgcn_mfma_f32_16x16x32_bf16(a2,b1,acc[2][1],0,0,0);
            acc[3][0] = __builtin_amdgcn_mfma_f32_16x16x32_bf16(a3,b0,acc[3][0],0,0,0);
            acc[3][1] = __builtin_amdgcn_mfma_f32_16x16x32_bf16(a3,b1,acc[3][1],0,0,0);
        }
    }

    // epilogue: BN + ReLU. D layout: col(px)=l&15, row(co)=(l>>4)*4+r
    int rbase = kb*4;
    #pragma unroll
    for (int mi = 0; mi < 4; mi++) {
        #pragma unroll
        for (int r = 0; r < 4; r++) {
            int co = wco + mi*16 + rbase + r;
            float sc = ws[SCALE_OFF+co], sh = ws[SHIFT_OFF+co];
            float* op = out + (size_t)(b*COc + co)*HW + pixbase + pxl;
            op[0]  = fmaxf(acc[mi][0][r]*sc + sh, 0.f);
            op[16] = fmaxf(acc[mi][1][r]*sc + sh, 0.f);
        }
    }
}

extern "C" void kernel_launch(void* const* d_in, const int* in_sizes, int n_in,
                              void* d_out, int out_size, void* d_ws, size_t ws_size,
                              hipStream_t stream) {
    const float* x     = (const float*)d_in[0];
    const float* w_off = (const float*)d_in[1];
    const float* b_off = (const float*)d_in[2];
    const float* w_dcn = (const float*)d_in[3];
    const float* b_dcn = (const float*)d_in[4];
    const float* gamma = (const float*)d_in[5];
    const float* beta  = (const float*)d_in[6];
    const float* rmean = (const float*)d_in[7];
    const float* rvar  = (const float*)d_in[8];
    float* out = (float*)d_out;
    float* ws  = (float*)d_ws;

    prep_kernel<<<512, 256, 0, stream>>>(w_off, w_dcn, b_dcn, gamma, beta, rmean, rvar, ws);
    offconv_kernel<<<512, 256, 0, stream>>>(x, b_off, ws);
    dconv_kernel<<<1024, 256, 0, stream>>>(x, ws, out);
}

// Round 3
// 165.676 us; speedup vs baseline: 12.5491x; 2.2842x over previous
//
#include <hip/hip_runtime.h>
#include <math.h>

#define Bn 2
#define CIc 256
#define COc 256
#define Hh 128
#define Ww 128
#define HW (Hh*Ww)

typedef unsigned short u16;
typedef unsigned int u32;
typedef __bf16 bf16x8 __attribute__((ext_vector_type(8)));
typedef float  f32x4  __attribute__((ext_vector_type(4)));
typedef float  f32x2  __attribute__((ext_vector_type(2)));
typedef u32    u32x4v __attribute__((ext_vector_type(4)));

// ws layout (float offsets)
#define WOFP_OFF  0          // 9*8*32*4*8 u16  = 36864 f
#define WPACK_OFF 36864      // 9*8*256*4*8 u16 = 294912 f
#define SCALE_OFF 331776
#define SHIFT_OFF 332032
#define XT_OFF    332288     // u16 xt[B][HW][256] = 8388608 u16 = 2097152 f
// total ws = 2429440 floats = 9.72 MB

__device__ __forceinline__ u16 f2bf(float f) {
    u32 u = __builtin_bit_cast(u32, f);
    return (u16)((u + 0x7FFFu + ((u >> 16) & 1u)) >> 16);
}
__device__ __forceinline__ u32 pkbf(float lo, float hi) {
    __bf16 a = (__bf16)lo, b = (__bf16)hi;            // compiler fuses to v_cvt_pk_bf16_f32
    return (u32)__builtin_bit_cast(u16, a) | ((u32)__builtin_bit_cast(u16, b) << 16);
}
__device__ __forceinline__ f32x2 unpk(u32 u) {
    f32x2 r;
    r.x = __builtin_bit_cast(float, u << 16);
    r.y = __builtin_bit_cast(float, u & 0xFFFF0000u);
    return r;
}

__global__ void prep_kernel(const float* __restrict__ w_off,
                            const float* __restrict__ w_dcn,
                            const float* __restrict__ b_dcn,
                            const float* __restrict__ gamma,
                            const float* __restrict__ beta,
                            const float* __restrict__ rmean,
                            const float* __restrict__ rvar,
                            float* __restrict__ ws) {
    int tid = blockIdx.x*blockDim.x + threadIdx.x;
    int nth = gridDim.x*blockDim.x;
    u16* wofp = (u16*)(ws + WOFP_OFF);
    u16* wpk  = (u16*)(ws + WPACK_OFF);
    // wofp: flat = (((k*8+s)*32+co)*4+kb)*8+j ; ci = s*32+kb*8+j ; co>=27 -> 0
    for (int idx = tid; idx < 9*8*32*4*8; idx += nth) {
        int j = idx & 7, kb = (idx>>3)&3, co = (idx>>5)&31, s = (idx>>10)&7, k = idx>>13;
        int ci = s*32 + kb*8 + j;
        float v = (co < 27) ? w_off[(co*CIc + ci)*9 + k] : 0.f;
        wofp[idx] = f2bf(v);
    }
    // wpk: flat = (((k*8+s)*256+co)*4+kb)*8+j
    for (int idx = tid; idx < 9*8*256*4*8; idx += nth) {
        int j = idx & 7, kb = (idx>>3)&3, co = (idx>>5)&255, s = (idx>>13)&7, k = idx>>16;
        int ci = s*32 + kb*8 + j;
        wpk[idx] = f2bf(w_dcn[(co*CIc + ci)*9 + k]);
    }
    if (tid < COc) {
        float inv = gamma[tid] * rsqrtf(rvar[tid] + 1e-5f);
        ws[SCALE_OFF+tid] = inv;
        ws[SHIFT_OFF+tid] = beta[tid] - rmean[tid]*inv + b_dcn[tid]*inv;
    }
}

// NCHW fp32 -> NHWC bf16 transpose. Block: 128px x 64ci tile.
__global__ __launch_bounds__(256) void transpose_kernel(const float* __restrict__ x,
                                                        float* __restrict__ ws) {
    __shared__ float tile[64][129];
    int bid = blockIdx.x;                // B * 128 * 4 = 1024
    int b   = bid >> 9;
    int pxt = (bid >> 2) & 127;
    int cit = bid & 3;
    const float* xb = x + ((size_t)(b*CIc + cit*64))*HW + pxt*128;
    int px = threadIdx.x & 127, cg = threadIdx.x >> 7;
    #pragma unroll 4
    for (int i2 = 0; i2 < 32; i2++) {
        int ci = cg*32 + i2;
        tile[ci][px] = xb[(size_t)ci*HW + px];
    }
    __syncthreads();
    int px2 = threadIdx.x >> 1, hf = threadIdx.x & 1;
    u16* xto = (u16*)(ws + XT_OFF) + ((size_t)b*HW + pxt*128 + px2)*256 + cit*64 + hf*32;
    u32x4v buf[4];
    #pragma unroll
    for (int i2 = 0; i2 < 16; i2++) {
        buf[i2>>2][i2&3] = pkbf(tile[hf*32 + 2*i2][px2], tile[hf*32 + 2*i2 + 1][px2]);
    }
    u32x4v* dst = (u32x4v*)xto;
    #pragma unroll
    for (int i2 = 0; i2 < 4; i2++) dst[i2] = buf[i2];
}

// Fused: phase A = offset conv (M=32, B-frags direct from global xt),
//        phase B = deformable conv (64px x 256co, val staged in LDS, 544B rows).
__global__ __launch_bounds__(256) void fused_kernel(const float* __restrict__ b_off,
                                                    const float* __restrict__ ws,
                                                    float* __restrict__ out) {
    __shared__ __align__(16) char smem[64*544 + 3*576*4];   // 41728 B
    float* fin = (float*)smem;                 // [32][64] f32, phase A only (aliases val)
    float* spy = (float*)(smem + 34816);
    float* spx = spy + 576;
    float* smk = spx + 576;

    int tid = threadIdx.x;
    int bid = blockIdx.x;
    int tile = (bid & 7)*64 + (bid >> 3);      // XCD-chunked swizzle, 512 blocks
    int b = tile >> 8;
    int pixbase = (tile & 255) * 64;
    int h  = pixbase >> 7;
    int w0 = pixbase & 127;

    const u16* wofp = (const u16*)(ws + WOFP_OFF);
    const u16* wpk  = (const u16*)(ws + WPACK_OFF);
    const u16* xt   = (const u16*)(ws + XT_OFF) + (size_t)b*HW*256;

    int l  = tid & 63;
    int wv = tid >> 6;
    int kb = l >> 4;
    int aoff = (l & 15)*32 + kb*8;

    // ---------------- phase A: offset conv ----------------
    {
        int pxa = wv*16 + (l & 15);            // pixel 0..63
        f32x4 oa0 = {0.f,0.f,0.f,0.f}, oa1 = {0.f,0.f,0.f,0.f};
        for (int k = 0; k < 9; k++) {
            int ky = k/3, kx = k - 3*ky;
            int y  = h + ky - 1;
            int xw = w0 + pxa + kx - 1;
            bool ok = ((unsigned)y < Hh) && ((unsigned)xw < Ww);
            const u16* brow = xt + (((y << 7) + xw) << 8);
            const u16* wk = wofp + k*8192;
            #pragma unroll
            for (int s = 0; s < 8; s++) {
                bf16x8 bf = {};
                if (ok) bf = *(const bf16x8*)(brow + s*32 + kb*8);
                bf16x8 a0 = *(const bf16x8*)(wk + s*1024 + aoff);
                bf16x8 a1 = *(const bf16x8*)(wk + s*1024 + 512 + aoff);
                oa0 = __builtin_amdgcn_mfma_f32_16x16x32_bf16(a0, bf, oa0, 0,0,0);
                oa1 = __builtin_amdgcn_mfma_f32_16x16x32_bf16(a1, bf, oa1, 0,0,0);
            }
        }
        #pragma unroll
        for (int r = 0; r < 4; r++) {
            fin[(kb*4 + r)*64 + pxa]      = oa0[r];
            fin[(16 + kb*4 + r)*64 + pxa] = oa1[r];
        }
    }
    __syncthreads();
    for (int idx = tid; idx < 576; idx += 256) {
        int k = idx >> 6, p = idx & 63;
        float dy = fin[(2*k)*64 + p]   + b_off[2*k];
        float dx = fin[(2*k+1)*64 + p] + b_off[2*k+1];
        float mv = fin[(18+k)*64 + p]  + b_off[18+k];
        spy[idx] = (float)(h - 1 + k/3) + dy;
        spx[idx] = (float)(w0 + p - 1 + k%3) + dx;
        smk[idx] = 1.f/(1.f + __expf(-mv));
    }
    __syncthreads();

    // ---------------- phase B: deformable conv ----------------
    int p_s = tid >> 2;                        // staging pixel 0..63
    int sub = tid & 3;                         // 64-ci chunk
    u32 wrbase = (u32)p_s*544 + (u32)sub*128;
    int pxl = l & 15;

    f32x4 acc[4][4];
    #pragma unroll
    for (int mi = 0; mi < 4; mi++)
        #pragma unroll
        for (int bq = 0; bq < 4; bq++)
            acc[mi][bq] = (f32x4){0.f,0.f,0.f,0.f};

    for (int k = 0; k < 9; k++) {
        float pyv = spy[k*64 + p_s], pxv = spx[k*64 + p_s], mv = smk[k*64 + p_s];
        float y0f = floorf(pyv), x0f = floorf(pxv);
        float ly = pyv - y0f, lx = pxv - x0f;
        int y0 = (int)y0f, x0i = (int)x0f;
        int y1 = y0 + 1, x1i = x0i + 1;
        float wy0 = ((unsigned)y0  < Hh) ? (1.f-ly) : 0.f;
        float wy1 = ((unsigned)y1  < Hh) ? ly       : 0.f;
        float wx0 = ((unsigned)x0i < Ww) ? (1.f-lx) : 0.f;
        float wx1 = ((unsigned)x1i < Ww) ? lx       : 0.f;
        float w00 = wy0*wx0*mv, w01 = wy0*wx1*mv, w10 = wy1*wx0*mv, w11 = wy1*wx1*mv;
        int cy0 = min(max(y0,0),Hh-1), cy1 = min(max(y1,0),Hh-1);
        int cx0 = min(max(x0i,0),Ww-1), cx1 = min(max(x1i,0),Ww-1);
        const u16* x00 = xt + ((((cy0<<7)+cx0)<<8) + sub*64);
        const u16* x01 = xt + ((((cy0<<7)+cx1)<<8) + sub*64);
        const u16* x10 = xt + ((((cy1<<7)+cx0)<<8) + sub*64);
        const u16* x11 = xt + ((((cy1<<7)+cx1)<<8) + sub*64);

        __syncthreads();                       // prev GEMM reads done
        #pragma unroll
        for (int it = 0; it < 8; it++) {
            u32x4v q00 = *(const u32x4v*)(x00 + (it<<3));
            u32x4v q01 = *(const u32x4v*)(x01 + (it<<3));
            u32x4v q10 = *(const u32x4v*)(x10 + (it<<3));
            u32x4v q11 = *(const u32x4v*)(x11 + (it<<3));
            u32x4v vv;
            #pragma unroll
            for (int w2 = 0; w2 < 4; w2++) {
                f32x2 r = unpk(q00[w2])*w00 + unpk(q01[w2])*w01
                        + unpk(q10[w2])*w10 + unpk(q11[w2])*w11;
                vv[w2] = pkbf(r.x, r.y);
            }
            *(u32x4v*)(smem + wrbase + (it<<4)) = vv;
        }
        __syncthreads();                       // val visible

        const u16* wkk = wpk + k*65536 + wv*2048 + aoff;
        #pragma unroll
        for (int s = 0; s < 8; s++) {
            bf16x8 a0 = *(const bf16x8*)(wkk + s*8192);
            bf16x8 a1 = *(const bf16x8*)(wkk + s*8192 + 512);
            bf16x8 a2 = *(const bf16x8*)(wkk + s*8192 + 1024);
            bf16x8 a3 = *(const bf16x8*)(wkk + s*8192 + 1536);
            #pragma unroll
            for (int bq = 0; bq < 4; bq++) {
                bf16x8 bb = *(const bf16x8*)(smem + (pxl + bq*16)*544 + s*64 + kb*16);
                acc[0][bq] = __builtin_amdgcn_mfma_f32_16x16x32_bf16(a0,bb,acc[0][bq],0,0,0);
                acc[1][bq] = __builtin_amdgcn_mfma_f32_16x16x32_bf16(a1,bb,acc[1][bq],0,0,0);
                acc[2][bq] = __builtin_amdgcn_mfma_f32_16x16x32_bf16(a2,bb,acc[2][bq],0,0,0);
                acc[3][bq] = __builtin_amdgcn_mfma_f32_16x16x32_bf16(a3,bb,acc[3][bq],0,0,0);
            }
        }
    }

    // epilogue: BN + ReLU. D layout: col(px)=l&15, row(co)=kb*4+r
    int rbase = kb*4;
    #pragma unroll
    for (int mi = 0; mi < 4; mi++) {
        #pragma unroll
        for (int r = 0; r < 4; r++) {
            int co = wv*64 + mi*16 + rbase + r;
            float sc = ws[SCALE_OFF+co], sh = ws[SHIFT_OFF+co];
            float* op = out + ((size_t)(b*COc + co))*HW + pixbase + pxl;
            #pragma unroll
            for (int bq = 0; bq < 4; bq++)
                op[bq*16] = fmaxf(acc[mi][bq][r]*sc + sh, 0.f);
        }
    }
}

extern "C" void kernel_launch(void* const* d_in, const int* in_sizes, int n_in,
                              void* d_out, int out_size, void* d_ws, size_t ws_size,
                              hipStream_t stream) {
    const float* x     = (const float*)d_in[0];
    const float* w_off = (const float*)d_in[1];
    const float* b_off = (const float*)d_in[2];
    const float* w_dcn = (const float*)d_in[3];
    const float* b_dcn = (const float*)d_in[4];
    const float* gamma = (const float*)d_in[5];
    const float* beta  = (const float*)d_in[6];
    const float* rmean = (const float*)d_in[7];
    const float* rvar  = (const float*)d_in[8];
    float* out = (float*)d_out;
    float* ws  = (float*)d_ws;

    prep_kernel<<<512, 256, 0, stream>>>(w_off, w_dcn, b_dcn, gamma, beta, rmean, rvar, ws);
    transpose_kernel<<<1024, 256, 0, stream>>>(x, ws);
    fused_kernel<<<512, 256, 0, stream>>>(b_off, ws, out);
}